// Round 1
// baseline (757.203 us; speedup 1.0000x reference)
//
#include <hip/hip_runtime.h>
#include <hip/hip_bf16.h>

// B=4, S=2048, D=2048, H=16, HD=128.  All fp32 in/out; internal compute bf16 MFMA.

typedef __attribute__((ext_vector_type(8))) short short8;
typedef __attribute__((ext_vector_type(4))) float floatx4;

#define DEV __device__ __forceinline__

DEV short f2bf(float f) {
    __hip_bfloat16 h = __float2bfloat16(f);
    return *reinterpret_cast<short*>(&h);
}

DEV void load_lds16(const __hip_bfloat16* g, short* l) {
    __builtin_amdgcn_global_load_lds(
        (const __attribute__((address_space(1))) void*)g,
        (__attribute__((address_space(3))) void*)l, 16, 0, 0);
}

// ---------------- cast x: fp32 -> bf16, 8 elems/thread ----------------
__global__ void cast_x_kernel(const float* __restrict__ in,
                              __hip_bfloat16* __restrict__ out, int n8) {
    int i = blockIdx.x * 256 + threadIdx.x;
    if (i >= n8) return;
    const float4* p = reinterpret_cast<const float4*>(in) + (size_t)i * 2;
    float4 a = p[0], b = p[1];
    short8 r;
    r[0] = f2bf(a.x); r[1] = f2bf(a.y); r[2] = f2bf(a.z); r[3] = f2bf(a.w);
    r[4] = f2bf(b.x); r[5] = f2bf(b.y); r[6] = f2bf(b.z); r[7] = f2bf(b.w);
    *reinterpret_cast<short8*>(reinterpret_cast<short*>(out) + (size_t)i * 8) = r;
}

// ------------- transpose-cast weights: wt[n][k] = w[k][n], bf16 -------------
// grid (64,64,4): z picks matrix (wq,wk,wv,wo); dst rows offset z*2048.
__global__ void transpose_cast_kernel(const float* __restrict__ wq,
                                      const float* __restrict__ wk,
                                      const float* __restrict__ wv,
                                      const float* __restrict__ wo,
                                      short* __restrict__ wt) {
    __shared__ float tile[32][33];
    const int z = blockIdx.z;
    const float* src = (z == 0) ? wq : (z == 1) ? wk : (z == 2) ? wv : wo;
    short* dst = wt + (size_t)z * 2048 * 2048;
    const int tx = threadIdx.x, ty = threadIdx.y;
    const int bx = blockIdx.x, by = blockIdx.y;
#pragma unroll
    for (int j = 0; j < 4; ++j)
        tile[ty + j * 8][tx] = src[(size_t)(by * 32 + ty + j * 8) * 2048 + bx * 32 + tx];
    __syncthreads();
#pragma unroll
    for (int j = 0; j < 4; ++j) {
        int r = ty + j * 8;
        dst[(size_t)(bx * 32 + r) * 2048 + by * 32 + tx] = f2bf(tile[tx][r]);
    }
}

// ---------------- GEMM: C[M][N] = A[M][2048] * Bt[N][2048]^T ----------------
// 128x128 tile, BK=64, 4 waves (2x2 of 64x64), m97 structure.
// LDS tiles XOR-swizzled: chunk' = chunk ^ (row&7); global source pre-swizzled
// so global_load_lds (linear dest) + swizzled ds_read are consistent (rule #21).
// MODE 0: QKV epilogue -> qbuf/kbuf [BH][S][HD] bf16, vtbuf [BH][HD][S] bf16 (+bias)
// MODE 1: out epilogue -> fp32 outf [M][2048] (+bias)
template<int MODE>
__launch_bounds__(256, 2)
__global__ void gemm_bt_kernel(const __hip_bfloat16* __restrict__ A,
                               const __hip_bfloat16* __restrict__ Bt,
                               const float* __restrict__ bias0,
                               const float* __restrict__ bias1,
                               const float* __restrict__ bias2,
                               short* __restrict__ qbuf,
                               short* __restrict__ kbuf,
                               short* __restrict__ vtbuf,
                               float* __restrict__ outf) {
    constexpr int K = 2048;
    __shared__ short As[128 * 64];
    __shared__ short Bs[128 * 64];
    const int t = threadIdx.x, lane = t & 63, wid = t >> 6;
    const int lr = lane & 15, lg = lane >> 4;
    const int n0 = blockIdx.x * 128, m0 = blockIdx.y * 128;
    const int wm = (wid & 1) * 64, wn = (wid >> 1) * 64;

    floatx4 acc[4][4];
#pragma unroll
    for (int i = 0; i < 4; ++i)
#pragma unroll
        for (int j = 0; j < 4; ++j) acc[i][j] = (floatx4){0.f, 0.f, 0.f, 0.f};

    for (int kt = 0; kt < K / 64; ++kt) {
        __syncthreads();
#pragma unroll
        for (int i = 0; i < 4; ++i) {  // A tile: 128 rows x 8 chunks of 16B
            int fc = i * 256 + t;
            int row = fc >> 3, p = fc & 7;
            int col = (p ^ (row & 7)) << 3;
            load_lds16(A + (size_t)(m0 + row) * K + kt * 64 + col,
                       &As[(i * 256 + wid * 64) * 8]);
        }
#pragma unroll
        for (int i = 0; i < 4; ++i) {  // B tile
            int fc = i * 256 + t;
            int row = fc >> 3, p = fc & 7;
            int col = (p ^ (row & 7)) << 3;
            load_lds16(Bt + (size_t)(n0 + row) * K + kt * 64 + col,
                       &Bs[(i * 256 + wid * 64) * 8]);
        }
        __syncthreads();
#pragma unroll
        for (int kk = 0; kk < 2; ++kk) {
            short8 af[4], bfr[4];
#pragma unroll
            for (int mi = 0; mi < 4; ++mi) {
                int row = wm + mi * 16 + lr;
                int c = lg + kk * 4;
                af[mi] = *(const short8*)&As[row * 64 + ((c ^ (row & 7)) << 3)];
            }
#pragma unroll
            for (int ni = 0; ni < 4; ++ni) {
                int row = wn + ni * 16 + lr;
                int c = lg + kk * 4;
                bfr[ni] = *(const short8*)&Bs[row * 64 + ((c ^ (row & 7)) << 3)];
            }
#pragma unroll
            for (int mi = 0; mi < 4; ++mi)
#pragma unroll
                for (int ni = 0; ni < 4; ++ni)
                    acc[mi][ni] = __builtin_amdgcn_mfma_f32_16x16x32_bf16(
                        af[mi], bfr[ni], acc[mi][ni], 0, 0, 0);
        }
    }

    // epilogue. C/D layout: col = lane&15, row = (lane>>4)*4 + reg  [m89/m91]
#pragma unroll
    for (int ni = 0; ni < 4; ++ni) {
        int n = n0 + wn + ni * 16 + lr;
        if (MODE == 0) {
            int which = n >> 11, d = n & 2047, h = d >> 7, hd = d & 127;
            const float* bias = (which == 0) ? bias0 : (which == 1) ? bias1 : bias2;
            float bval = bias[d];
            short* buf = (which == 0) ? qbuf : (which == 1) ? kbuf : vtbuf;
#pragma unroll
            for (int mi = 0; mi < 4; ++mi) {
                int m = m0 + wm + mi * 16 + lg * 4;
                int b = m >> 11, s = m & 2047;
                int bh = b * 16 + h;
#pragma unroll
                for (int r = 0; r < 4; ++r) {
                    float v = acc[mi][ni][r] + bval;
                    if (which < 2)
                        buf[((size_t)bh * 2048 + s + r) * 128 + hd] = f2bf(v);
                    else  // V stored transposed: [BH][HD][S]
                        buf[((size_t)bh * 128 + hd) * 2048 + s + r] = f2bf(v);
                }
            }
        } else {
            float bval = bias0[n];
#pragma unroll
            for (int mi = 0; mi < 4; ++mi) {
                int m = m0 + wm + mi * 16 + lg * 4;
#pragma unroll
                for (int r = 0; r < 4; ++r)
                    outf[(size_t)(m + r) * 2048 + n] = acc[mi][ni][r] + bval;
            }
        }
    }
}

// ---------------- flash attention ----------------
// grid (S/128, B*H); 4 waves x 32 q-rows. KVBLK=64.
// Q in registers; K [64][128] and Vt [128][64] staged via swizzled global_load_lds;
// online softmax in-register on C-layout; P bounced through per-wave swizzled LDS.
__launch_bounds__(256, 2)
__global__ void attn_kernel(const __hip_bfloat16* __restrict__ qb,
                            const __hip_bfloat16* __restrict__ kb,
                            const __hip_bfloat16* __restrict__ vtb,
                            short* __restrict__ ob) {
    __shared__ short Ks[64 * 128];   // 16KB, 16 chunks/row, swizzle ^(row&15)
    __shared__ short Vts[128 * 64];  // 16KB, 8 chunks/row,  swizzle ^(row&7)
    __shared__ short Ps[4][32 * 64]; // per-wave P, swizzle ^(row&7)
    const int t = threadIdx.x, lane = t & 63, w = t >> 6;
    const int lr = lane & 15, lg = lane >> 4;
    const int bh = blockIdx.y, b = bh >> 4, h = bh & 15;
    const int q0 = blockIdx.x * 128;
    const __hip_bfloat16* qB = qb + (size_t)bh * 2048 * 128;
    const __hip_bfloat16* kB = kb + (size_t)bh * 2048 * 128;
    const __hip_bfloat16* vB = vtb + (size_t)bh * 128 * 2048;

    // Q fragments: wave owns rows q0 + w*32 + [0,32)
    short8 aq[2][4];
#pragma unroll
    for (int mi = 0; mi < 2; ++mi) {
        int row = q0 + w * 32 + mi * 16 + lr;
#pragma unroll
        for (int kk = 0; kk < 4; ++kk)
            aq[mi][kk] = *(const short8*)(qB + (size_t)row * 128 + lg * 8 + kk * 32);
    }

    floatx4 o[2][8];
    float mv[2][4], lv[2][4];
#pragma unroll
    for (int mi = 0; mi < 2; ++mi) {
#pragma unroll
        for (int n = 0; n < 8; ++n) o[mi][n] = (floatx4){0.f, 0.f, 0.f, 0.f};
#pragma unroll
        for (int r = 0; r < 4; ++r) { mv[mi][r] = -1e30f; lv[mi][r] = 0.f; }
    }
    const float scale = 0.08838834764831845f;  // 1/sqrt(128)

    for (int kv = 0; kv < 32; ++kv) {
        __syncthreads();
#pragma unroll
        for (int i = 0; i < 4; ++i) {  // K tile: 64 rows x 16 chunks
            int fc = i * 256 + t, row = fc >> 4, p = fc & 15;
            load_lds16(kB + (size_t)(kv * 64 + row) * 128 + ((p ^ (row & 15)) << 3),
                       &Ks[(i * 256 + w * 64) * 8]);
        }
#pragma unroll
        for (int i = 0; i < 4; ++i) {  // Vt tile: 128 rows x 8 chunks
            int fc = i * 256 + t, row = fc >> 3, p = fc & 7;
            load_lds16(vB + (size_t)row * 2048 + kv * 64 + ((p ^ (row & 7)) << 3),
                       &Vts[(i * 256 + w * 64) * 8]);
        }
        __syncthreads();

#pragma unroll
        for (int mi = 0; mi < 2; ++mi) {
            floatx4 sfr[4];
#pragma unroll
            for (int tt = 0; tt < 4; ++tt) {
                floatx4 a = {0.f, 0.f, 0.f, 0.f};
#pragma unroll
                for (int kk = 0; kk < 4; ++kk) {
                    int row = tt * 16 + lr;
                    int c = lg + kk * 4;
                    short8 bk = *(const short8*)&Ks[row * 128 + ((c ^ (row & 15)) << 3)];
                    a = __builtin_amdgcn_mfma_f32_16x16x32_bf16(aq[mi][kk], bk, a, 0, 0, 0);
                }
                sfr[tt] = a * scale;
            }
            // online softmax; row r lives in this lane's 16-lane group
#pragma unroll
            for (int r = 0; r < 4; ++r) {
                float pm = fmaxf(fmaxf(sfr[0][r], sfr[1][r]), fmaxf(sfr[2][r], sfr[3][r]));
                pm = fmaxf(pm, __shfl_xor(pm, 1));
                pm = fmaxf(pm, __shfl_xor(pm, 2));
                pm = fmaxf(pm, __shfl_xor(pm, 4));
                pm = fmaxf(pm, __shfl_xor(pm, 8));
                float mn = fmaxf(mv[mi][r], pm);
                float alpha = __expf(mv[mi][r] - mn);
                mv[mi][r] = mn;
                float ls = 0.f;
#pragma unroll
                for (int tt = 0; tt < 4; ++tt) {
                    float p = __expf(sfr[tt][r] - mn);
                    sfr[tt][r] = p;
                    ls += p;
                }
                ls += __shfl_xor(ls, 1);
                ls += __shfl_xor(ls, 2);
                ls += __shfl_xor(ls, 4);
                ls += __shfl_xor(ls, 8);
                lv[mi][r] = lv[mi][r] * alpha + ls;
#pragma unroll
                for (int n = 0; n < 8; ++n) o[mi][n][r] *= alpha;
            }
            // P -> per-wave LDS (C-layout write, swizzled)
#pragma unroll
            for (int tt = 0; tt < 4; ++tt)
#pragma unroll
                for (int r = 0; r < 4; ++r) {
                    int row = mi * 16 + lg * 4 + r;
                    int cc = tt * 2 + (lr >> 3);
                    Ps[w][row * 64 + ((cc ^ (row & 7)) << 3) + (lane & 7)] =
                        f2bf(sfr[tt][r]);
                }
        }
        // PV: read P back in A-layout, V columns from Vt rows
#pragma unroll
        for (int mi = 0; mi < 2; ++mi) {
            short8 pa[2];
#pragma unroll
            for (int kk = 0; kk < 2; ++kk) {
                int row = mi * 16 + lr;
                int c = lg + kk * 4;
                pa[kk] = *(const short8*)&Ps[w][row * 64 + ((c ^ (row & 7)) << 3)];
            }
#pragma unroll
            for (int n = 0; n < 8; ++n) {
#pragma unroll
                for (int kk = 0; kk < 2; ++kk) {
                    int vrow = n * 16 + lr;
                    int c = lg + kk * 4;
                    short8 bv = *(const short8*)&Vts[vrow * 64 + ((c ^ (vrow & 7)) << 3)];
                    o[mi][n] = __builtin_amdgcn_mfma_f32_16x16x32_bf16(pa[kk], bv, o[mi][n], 0, 0, 0);
                }
            }
        }
    }

    // epilogue: normalize, write O_merged [B*S][D] bf16 (col = h*128+hd)
#pragma unroll
    for (int mi = 0; mi < 2; ++mi)
#pragma unroll
        for (int r = 0; r < 4; ++r) {
            float inv = 1.f / lv[mi][r];
            int srow = q0 + w * 32 + mi * 16 + lg * 4 + r;
            size_t base = ((size_t)b * 2048 + srow) * 2048 + h * 128;
#pragma unroll
            for (int n = 0; n < 8; ++n)
                ob[base + n * 16 + lr] = f2bf(o[mi][n][r] * inv);
        }
}

extern "C" void kernel_launch(void* const* d_in, const int* in_sizes, int n_in,
                              void* d_out, int out_size, void* d_ws, size_t ws_size,
                              hipStream_t stream) {
    (void)in_sizes; (void)n_in; (void)out_size; (void)ws_size;
    const float* x  = (const float*)d_in[0];
    const float* wq = (const float*)d_in[1];
    const float* bq = (const float*)d_in[2];
    const float* wk = (const float*)d_in[3];
    const float* bk = (const float*)d_in[4];
    const float* wv = (const float*)d_in[5];
    const float* bv = (const float*)d_in[6];
    const float* wo = (const float*)d_in[7];
    const float* bo = (const float*)d_in[8];
    float* out = (float*)d_out;

    char* ws = (char*)d_ws;
    const size_t SZ = (size_t)33554432;  // 8192*2048*2 bytes
    __hip_bfloat16* xbf = (__hip_bfloat16*)(ws);          // x bf16 [8192][2048]
    short* wt    = (short*)(ws + SZ);                     // Wt: 4 x [2048][2048] bf16 (q,k,v,o)
    short* qbuf  = (short*)(ws + 2 * SZ);                 // [BH][S][HD]
    short* kbuf  = (short*)(ws + 3 * SZ);                 // [BH][S][HD]
    short* vtbuf = (short*)(ws + 4 * SZ);                 // [BH][HD][S]
    short* obuf  = (short*)(ws);                          // aliases xbf (dead after gemm<0>)

    cast_x_kernel<<<8192, 256, 0, stream>>>(x, xbf, 2097152);
    transpose_cast_kernel<<<dim3(64, 64, 4), dim3(32, 8), 0, stream>>>(wq, wk, wv, wo, wt);
    gemm_bt_kernel<0><<<dim3(48, 64), 256, 0, stream>>>(
        xbf, (const __hip_bfloat16*)wt, bq, bk, bv, qbuf, kbuf, vtbuf, nullptr);
    attn_kernel<<<dim3(16, 64), 256, 0, stream>>>(
        (const __hip_bfloat16*)qbuf, (const __hip_bfloat16*)kbuf,
        (const __hip_bfloat16*)vtbuf, obuf);
    gemm_bt_kernel<1><<<dim3(16, 64), 256, 0, stream>>>(
        (const __hip_bfloat16*)obuf, (const __hip_bfloat16*)(wt + (size_t)6144 * 2048),
        bo, nullptr, nullptr, nullptr, nullptr, nullptr, out);
}

// Round 3
// 672.729 us; speedup vs baseline: 1.1256x; 1.1256x over previous
//
#include <hip/hip_runtime.h>
#include <hip/hip_bf16.h>

// B=4, S=2048, D=2048, H=16, HD=128.  fp32 in/out; internal bf16 MFMA.

typedef __attribute__((ext_vector_type(8))) short short8;
typedef __attribute__((ext_vector_type(4))) short short4v;
typedef __attribute__((ext_vector_type(4))) float floatx4;
typedef unsigned int u32;

#define DEV __device__ __forceinline__

DEV short f2bf(float f) {
    __hip_bfloat16 h = __float2bfloat16(f);
    return *reinterpret_cast<short*>(&h);
}

DEV void load_lds16(const __hip_bfloat16* g, short* l) {
    __builtin_amdgcn_global_load_lds(
        (const __attribute__((address_space(1))) void*)g,
        (__attribute__((address_space(3))) void*)l, 16, 0, 0);
}

DEV u32 cvt_pk_bf16(float lo, float hi) {  // D[15:0]=bf16(lo), D[31:16]=bf16(hi)
    u32 r;
    asm("v_cvt_pk_bf16_f32 %0, %1, %2" : "=v"(r) : "v"(lo), "v"(hi));
    return r;
}

// ---------------- cast x: fp32 -> bf16, 8 elems/thread ----------------
__global__ void cast_x_kernel(const float* __restrict__ in,
                              __hip_bfloat16* __restrict__ out, int n8) {
    int i = blockIdx.x * 256 + threadIdx.x;
    if (i >= n8) return;
    const float4* p = reinterpret_cast<const float4*>(in) + (size_t)i * 2;
    float4 a = p[0], b = p[1];
    short8 r;
    r[0] = f2bf(a.x); r[1] = f2bf(a.y); r[2] = f2bf(a.z); r[3] = f2bf(a.w);
    r[4] = f2bf(b.x); r[5] = f2bf(b.y); r[6] = f2bf(b.z); r[7] = f2bf(b.w);
    *reinterpret_cast<short8*>(reinterpret_cast<short*>(out) + (size_t)i * 8) = r;
}

// ------------- transpose-cast weights: wt[n][k] = w[k][n], bf16 -------------
__global__ void transpose_cast_kernel(const float* __restrict__ wq,
                                      const float* __restrict__ wk,
                                      const float* __restrict__ wv,
                                      const float* __restrict__ wo,
                                      short* __restrict__ wt) {
    __shared__ float tile[32][33];
    const int z = blockIdx.z;
    const float* src = (z == 0) ? wq : (z == 1) ? wk : (z == 2) ? wv : wo;
    short* dst = wt + (size_t)z * 2048 * 2048;
    const int tx = threadIdx.x, ty = threadIdx.y;
    const int bx = blockIdx.x, by = blockIdx.y;
#pragma unroll
    for (int j = 0; j < 4; ++j)
        tile[ty + j * 8][tx] = src[(size_t)(by * 32 + ty + j * 8) * 2048 + bx * 32 + tx];
    __syncthreads();
#pragma unroll
    for (int j = 0; j < 4; ++j) {
        int r = ty + j * 8;
        dst[(size_t)(bx * 32 + r) * 2048 + by * 32 + tx] = f2bf(tile[tx][r]);
    }
}

// ---------------- GEMM: C[M][N] = A[M][2048] * Bt[N][2048]^T ----------------
// 128x128 tile, BK=64, 4 waves, m97 structure; LDS XOR-swizzled both-sides.
// MODE 0: QKV epilogue (Q pre-scaled by 1/sqrt(HD)); MODE 1: fp32 out + bias.
template<int MODE>
__launch_bounds__(256, 2)
__global__ void gemm_bt_kernel(const __hip_bfloat16* __restrict__ A,
                               const __hip_bfloat16* __restrict__ Bt,
                               const float* __restrict__ bias0,
                               const float* __restrict__ bias1,
                               const float* __restrict__ bias2,
                               short* __restrict__ qbuf,
                               short* __restrict__ kbuf,
                               short* __restrict__ vtbuf,
                               float* __restrict__ outf) {
    constexpr int K = 2048;
    __shared__ short As[128 * 64];
    __shared__ short Bs[128 * 64];
    const int t = threadIdx.x, lane = t & 63, wid = t >> 6;
    const int lr = lane & 15, lg = lane >> 4;
    const int n0 = blockIdx.x * 128, m0 = blockIdx.y * 128;
    const int wm = (wid & 1) * 64, wn = (wid >> 1) * 64;

    floatx4 acc[4][4];
#pragma unroll
    for (int i = 0; i < 4; ++i)
#pragma unroll
        for (int j = 0; j < 4; ++j) acc[i][j] = (floatx4){0.f, 0.f, 0.f, 0.f};

    for (int kt = 0; kt < K / 64; ++kt) {
        __syncthreads();
#pragma unroll
        for (int i = 0; i < 4; ++i) {
            int fc = i * 256 + t;
            int row = fc >> 3, p = fc & 7;
            int col = (p ^ (row & 7)) << 3;
            load_lds16(A + (size_t)(m0 + row) * K + kt * 64 + col,
                       &As[(i * 256 + wid * 64) * 8]);
        }
#pragma unroll
        for (int i = 0; i < 4; ++i) {
            int fc = i * 256 + t;
            int row = fc >> 3, p = fc & 7;
            int col = (p ^ (row & 7)) << 3;
            load_lds16(Bt + (size_t)(n0 + row) * K + kt * 64 + col,
                       &Bs[(i * 256 + wid * 64) * 8]);
        }
        __syncthreads();
#pragma unroll
        for (int kk = 0; kk < 2; ++kk) {
            short8 af[4], bfr[4];
#pragma unroll
            for (int mi = 0; mi < 4; ++mi) {
                int row = wm + mi * 16 + lr;
                int c = lg + kk * 4;
                af[mi] = *(const short8*)&As[row * 64 + ((c ^ (row & 7)) << 3)];
            }
#pragma unroll
            for (int ni = 0; ni < 4; ++ni) {
                int row = wn + ni * 16 + lr;
                int c = lg + kk * 4;
                bfr[ni] = *(const short8*)&Bs[row * 64 + ((c ^ (row & 7)) << 3)];
            }
#pragma unroll
            for (int mi = 0; mi < 4; ++mi)
#pragma unroll
                for (int ni = 0; ni < 4; ++ni)
                    acc[mi][ni] = __builtin_amdgcn_mfma_f32_16x16x32_bf16(
                        af[mi], bfr[ni], acc[mi][ni], 0, 0, 0);
        }
    }

#pragma unroll
    for (int ni = 0; ni < 4; ++ni) {
        int n = n0 + wn + ni * 16 + lr;
        if (MODE == 0) {
            int which = n >> 11, d = n & 2047, h = d >> 7, hd = d & 127;
            const float* bias = (which == 0) ? bias0 : (which == 1) ? bias1 : bias2;
            float bval = bias[d];
            short* buf = (which == 0) ? qbuf : (which == 1) ? kbuf : vtbuf;
#pragma unroll
            for (int mi = 0; mi < 4; ++mi) {
                int m = m0 + wm + mi * 16 + lg * 4;
                int b = m >> 11, s = m & 2047;
                int bh = b * 16 + h;
#pragma unroll
                for (int r = 0; r < 4; ++r) {
                    float v = acc[mi][ni][r] + bval;
                    if (which == 0) v *= 0.08838834764831845f;  // fold QK scale
                    if (which < 2)
                        buf[((size_t)bh * 2048 + s + r) * 128 + hd] = f2bf(v);
                    else
                        buf[((size_t)bh * 128 + hd) * 2048 + s + r] = f2bf(v);
                }
            }
        } else {
            float bval = bias0[n];
#pragma unroll
            for (int mi = 0; mi < 4; ++mi) {
                int m = m0 + wm + mi * 16 + lg * 4;
#pragma unroll
                for (int r = 0; r < 4; ++r)
                    outf[(size_t)(m + r) * 2048 + n] = acc[mi][ni][r] + bval;
            }
        }
    }
}

// ---------------- flash attention (swapped-QK^T, 2-phase dbuf) ----------------
// grid (16, 64); 4 waves x 32 q-rows (QBLK=128), KVBLK=64.
// S^T = mfma(K,Q): q lane-local -> in-lane softmax; P^T packed b64 into Pt;
// O^T accumulated; K/V double-buffered via global_load_lds + raw barrier/vmcnt.
__launch_bounds__(256, 2)
__global__ void attn_kernel(const __hip_bfloat16* __restrict__ qb,
                            const __hip_bfloat16* __restrict__ kb,
                            const __hip_bfloat16* __restrict__ vtb,
                            short* __restrict__ ob) {
    __shared__ short Ks[2][64 * 128];   // 2x16KB, swizzle ^(row&15) on 16B chunks
    __shared__ short Vts[2][128 * 64];  // 2x16KB, swizzle ^(row&7)
    __shared__ short Pt[4][32 * 64];    // per-wave P^T as [q][kv], swizzle ^(lr&7)

    const int t = threadIdx.x, lane = t & 63, w = t >> 6;
    const int lr = lane & 15, lg = lane >> 4;

    // XCD swizzle: all 16 q-blocks of a head on one XCD (id%8 == XCD).
    int id = blockIdx.y * 16 + blockIdx.x;
    int xcd = id & 7, slot = id >> 3;
    int bh = xcd * 8 + (slot >> 4);
    int qblk = slot & 15;
    const int b = bh >> 4, h = bh & 15;
    const int q0 = qblk * 128;

    const __hip_bfloat16* qB = qb + (size_t)bh * 2048 * 128;
    const __hip_bfloat16* kB = kb + (size_t)bh * 2048 * 128;
    const __hip_bfloat16* vB = vtb + (size_t)bh * 128 * 2048;

    // Q fragments (pre-scaled in projection): rows q0 + w*32 + mi*16 + lr
    short8 aq[2][4];
#pragma unroll
    for (int mi = 0; mi < 2; ++mi) {
        int row = q0 + w * 32 + mi * 16 + lr;
#pragma unroll
        for (int kk = 0; kk < 4; ++kk)
            aq[mi][kk] = *(const short8*)(qB + (size_t)row * 128 + lg * 8 + kk * 32);
    }

    floatx4 o[2][8];
    float mv[2], lv[2];
#pragma unroll
    for (int mi = 0; mi < 2; ++mi) {
#pragma unroll
        for (int n = 0; n < 8; ++n) o[mi][n] = (floatx4){0.f, 0.f, 0.f, 0.f};
        mv[mi] = -1e30f; lv[mi] = 0.f;
    }

    auto STAGE = [&](int d, int kv) {
#pragma unroll
        for (int i = 0; i < 4; ++i) {  // K tile: 64 rows x 16 chunks
            int fc = i * 256 + t, row = fc >> 4, p = fc & 15;
            load_lds16(kB + (size_t)(kv * 64 + row) * 128 + ((p ^ (row & 15)) << 3),
                       &Ks[d][(i * 256 + w * 64) * 8]);
        }
#pragma unroll
        for (int i = 0; i < 4; ++i) {  // Vt tile: 128 rows x 8 chunks
            int fc = i * 256 + t, row = fc >> 3, p = fc & 7;
            load_lds16(vB + (size_t)row * 2048 + kv * 64 + ((p ^ (row & 7)) << 3),
                       &Vts[d][(i * 256 + w * 64) * 8]);
        }
    };

    STAGE(0, 0);
    asm volatile("s_waitcnt vmcnt(0)" ::: "memory");
    __builtin_amdgcn_s_barrier();

    int cur = 0;
    for (int kv = 0; kv < 32; ++kv) {
        if (kv < 31) STAGE(cur ^ 1, kv + 1);  // prefetch next tile (in flight)

        // ---- QK^T (swapped): sfr[mi][tt] = S^T tile, col=q(lr), row=kv(lg*4+r)
        floatx4 sfr[2][4];
#pragma unroll
        for (int mi = 0; mi < 2; ++mi)
#pragma unroll
            for (int tt = 0; tt < 4; ++tt) sfr[mi][tt] = (floatx4){0.f, 0.f, 0.f, 0.f};
        __builtin_amdgcn_s_setprio(1);
#pragma unroll
        for (int tt = 0; tt < 4; ++tt)
#pragma unroll
            for (int kk = 0; kk < 4; ++kk) {
                int row = tt * 16 + lr;
                int c = lg + kk * 4;
                short8 bk = *(const short8*)&Ks[cur][row * 128 + ((c ^ (row & 15)) << 3)];
                sfr[0][tt] = __builtin_amdgcn_mfma_f32_16x16x32_bf16(bk, aq[0][kk], sfr[0][tt], 0, 0, 0);
                sfr[1][tt] = __builtin_amdgcn_mfma_f32_16x16x32_bf16(bk, aq[1][kk], sfr[1][tt], 0, 0, 0);
            }
        __builtin_amdgcn_s_setprio(0);

        // ---- online softmax, in-lane over 16 kv + cross-lg reduce
#pragma unroll
        for (int mi = 0; mi < 2; ++mi) {
            float pm = sfr[mi][0][0];
#pragma unroll
            for (int tt = 0; tt < 4; ++tt)
#pragma unroll
                for (int r = 0; r < 4; ++r) pm = fmaxf(pm, sfr[mi][tt][r]);
            pm = fmaxf(pm, __shfl_xor(pm, 16));
            pm = fmaxf(pm, __shfl_xor(pm, 32));
            if (!__all(pm - mv[mi] <= 8.f)) {  // defer-max (THR=8)
                float mn = fmaxf(mv[mi], pm);
                float alpha = __expf(mv[mi] - mn);
                mv[mi] = mn;
                lv[mi] *= alpha;
#pragma unroll
                for (int n = 0; n < 8; ++n) o[mi][n] *= alpha;
            }
            float m = mv[mi], ls = 0.f;
            u32 pk[8];
#pragma unroll
            for (int tt = 0; tt < 4; ++tt) {
                float p0 = __expf(sfr[mi][tt][0] - m);
                float p1 = __expf(sfr[mi][tt][1] - m);
                float p2 = __expf(sfr[mi][tt][2] - m);
                float p3 = __expf(sfr[mi][tt][3] - m);
                ls += (p0 + p1) + (p2 + p3);
                pk[tt * 2] = cvt_pk_bf16(p0, p1);
                pk[tt * 2 + 1] = cvt_pk_bf16(p2, p3);
            }
            ls += __shfl_xor(ls, 16);
            ls += __shfl_xor(ls, 32);
            lv[mi] += ls;
            // P^T -> Pt[q=mi*16+lr][kv], packed b64, 16B-granule swizzle ^(lr&7)
#pragma unroll
            for (int tt = 0; tt < 4; ++tt) {
                int hgran = tt * 2 + (lg >> 1);
                int idx = (mi * 16 + lr) * 64 + ((hgran ^ (lr & 7)) * 8) + (lg & 1) * 4;
                *(uint2*)&Pt[w][idx] = make_uint2(pk[tt * 2], pk[tt * 2 + 1]);
            }
        }

        // ---- PV: O^T += V^T-frag x P^T-frag
        short8 pa[2][2];
#pragma unroll
        for (int mi = 0; mi < 2; ++mi)
#pragma unroll
            for (int kk = 0; kk < 2; ++kk) {
                int hgran = kk * 4 + lg;
                int idx = (mi * 16 + lr) * 64 + ((hgran ^ (lr & 7)) * 8);
                pa[mi][kk] = *(const short8*)&Pt[w][idx];
            }
        __builtin_amdgcn_s_setprio(1);
#pragma unroll
        for (int n = 0; n < 8; ++n)
#pragma unroll
            for (int kk = 0; kk < 2; ++kk) {
                int vrow = n * 16 + lr;
                int c = lg + kk * 4;
                short8 bv = *(const short8*)&Vts[cur][vrow * 64 + ((c ^ (vrow & 7)) << 3)];
                o[0][n] = __builtin_amdgcn_mfma_f32_16x16x32_bf16(bv, pa[0][kk], o[0][n], 0, 0, 0);
                o[1][n] = __builtin_amdgcn_mfma_f32_16x16x32_bf16(bv, pa[1][kk], o[1][n], 0, 0, 0);
            }
        __builtin_amdgcn_s_setprio(0);

        asm volatile("s_waitcnt vmcnt(0)" ::: "memory");  // next tile landed
        __builtin_amdgcn_s_barrier();
        cur ^= 1;
    }

    // ---- epilogue: O[s][h*128+d] = O^T[d][q]/l, packed 4-bf16 stores
#pragma unroll
    for (int mi = 0; mi < 2; ++mi) {
        float inv = 1.f / lv[mi];
        int s = q0 + w * 32 + mi * 16 + lr;
        size_t base = ((size_t)b * 2048 + s) * 2048 + h * 128;
#pragma unroll
        for (int n = 0; n < 8; ++n) {
            short4v vv;
#pragma unroll
            for (int r = 0; r < 4; ++r) vv[r] = f2bf(o[mi][n][r] * inv);
            *(short4v*)&ob[base + n * 16 + lg * 4] = vv;
        }
    }
}

extern "C" void kernel_launch(void* const* d_in, const int* in_sizes, int n_in,
                              void* d_out, int out_size, void* d_ws, size_t ws_size,
                              hipStream_t stream) {
    (void)in_sizes; (void)n_in; (void)out_size; (void)ws_size;
    const float* x  = (const float*)d_in[0];
    const float* wq = (const float*)d_in[1];
    const float* bq = (const float*)d_in[2];
    const float* wk = (const float*)d_in[3];
    const float* bk = (const float*)d_in[4];
    const float* wv = (const float*)d_in[5];
    const float* bv = (const float*)d_in[6];
    const float* wo = (const float*)d_in[7];
    const float* bo = (const float*)d_in[8];
    float* out = (float*)d_out;

    char* ws = (char*)d_ws;
    const size_t SZ = (size_t)33554432;  // 8192*2048*2 bytes
    __hip_bfloat16* xbf = (__hip_bfloat16*)(ws);
    short* wt    = (short*)(ws + SZ);
    short* qbuf  = (short*)(ws + 2 * SZ);
    short* kbuf  = (short*)(ws + 3 * SZ);
    short* vtbuf = (short*)(ws + 4 * SZ);
    short* obuf  = (short*)(ws);  // aliases xbf (dead after gemm<0>)

    cast_x_kernel<<<8192, 256, 0, stream>>>(x, xbf, 2097152);
    transpose_cast_kernel<<<dim3(64, 64, 4), dim3(32, 8), 0, stream>>>(wq, wk, wv, wo, wt);
    gemm_bt_kernel<0><<<dim3(48, 64), 256, 0, stream>>>(
        xbf, (const __hip_bfloat16*)wt, bq, bk, bv, qbuf, kbuf, vtbuf, nullptr);
    attn_kernel<<<dim3(16, 64), 256, 0, stream>>>(
        (const __hip_bfloat16*)qbuf, (const __hip_bfloat16*)kbuf,
        (const __hip_bfloat16*)vtbuf, obuf);
    gemm_bt_kernel<1><<<dim3(16, 64), 256, 0, stream>>>(
        (const __hip_bfloat16*)obuf, (const __hip_bfloat16*)(wt + (size_t)6144 * 2048),
        bo, nullptr, nullptr, nullptr, nullptr, nullptr, out);
}

// Round 7
// 640.944 us; speedup vs baseline: 1.1814x; 1.0496x over previous
//
#include <hip/hip_runtime.h>
#include <hip/hip_bf16.h>

// B=4, S=2048, D=2048, H=16, HD=128.  fp32 in/out; internal bf16 MFMA.

typedef __attribute__((ext_vector_type(8))) short short8;
typedef __attribute__((ext_vector_type(4))) short short4v;
typedef __attribute__((ext_vector_type(4))) float floatx4;
typedef unsigned int u32;

#define DEV __device__ __forceinline__

DEV short f2bf(float f) {
    __hip_bfloat16 h = __float2bfloat16(f);
    return *reinterpret_cast<short*>(&h);
}

DEV void load_lds16(const __hip_bfloat16* g, short* l) {
    __builtin_amdgcn_global_load_lds(
        (const __attribute__((address_space(1))) void*)g,
        (__attribute__((address_space(3))) void*)l, 16, 0, 0);
}

DEV u32 cvt_pk_bf16(float lo, float hi) {
    u32 r;
    asm("v_cvt_pk_bf16_f32 %0, %1, %2" : "=v"(r) : "v"(lo), "v"(hi));
    return r;
}

// ---------------- cast x: fp32 -> bf16, 8 elems/thread ----------------
__global__ void cast_x_kernel(const float* __restrict__ in,
                              __hip_bfloat16* __restrict__ out, int n8) {
    int i = blockIdx.x * 256 + threadIdx.x;
    if (i >= n8) return;
    const float4* p = reinterpret_cast<const float4*>(in) + (size_t)i * 2;
    float4 a = p[0], b = p[1];
    short8 r;
    r[0] = f2bf(a.x); r[1] = f2bf(a.y); r[2] = f2bf(a.z); r[3] = f2bf(a.w);
    r[4] = f2bf(b.x); r[5] = f2bf(b.y); r[6] = f2bf(b.z); r[7] = f2bf(b.w);
    *reinterpret_cast<short8*>(reinterpret_cast<short*>(out) + (size_t)i * 8) = r;
}

// ------------- transpose-cast weights: wt[n][k] = w[k][n], bf16 -------------
__global__ void transpose_cast_kernel(const float* __restrict__ wq,
                                      const float* __restrict__ wk,
                                      const float* __restrict__ wv,
                                      const float* __restrict__ wo,
                                      short* __restrict__ wt) {
    __shared__ float tile[32][33];
    const int z = blockIdx.z;
    const float* src = (z == 0) ? wq : (z == 1) ? wk : (z == 2) ? wv : wo;
    short* dst = wt + (size_t)z * 2048 * 2048;
    const int tx = threadIdx.x, ty = threadIdx.y;
    const int bx = blockIdx.x, by = blockIdx.y;
#pragma unroll
    for (int j = 0; j < 4; ++j)
        tile[ty + j * 8][tx] = src[(size_t)(by * 32 + ty + j * 8) * 2048 + bx * 32 + tx];
    __syncthreads();
#pragma unroll
    for (int j = 0; j < 4; ++j) {
        int r = ty + j * 8;
        dst[(size_t)(bx * 32 + r) * 2048 + by * 32 + tx] = f2bf(tile[tx][r]);
    }
}

// ======== 256x256 8-phase GEMM: C[M][N] = A[M][2048] * Bt[N][2048]^T ========
// 8 waves (2M x 4N), BK=64, per-wave out 128x64 (two 64-row x two 32-col bands).
// LDS: per matrix 2 slots x 2 halves x [128 rows][64 cols] bf16, chunk^=(row&7)
// swizzle via pre-swizzled global source (rule #21). 8 phases / 2 K-tiles, each:
// {ds_read subtile | stage 1 half-tile | barrier | lgkmcnt(0) | 16 MFMA | barrier},
// counted vmcnt(4) only at phases 4/8 (T3+T4); setprio around MFMA (T5).
// MODE 0: QKV scatter epilogue (Q pre-scaled); MODE 1: fp32 out + bias.
template<int MODE>
__launch_bounds__(512, 1)
__global__ void gemm256_kernel(const __hip_bfloat16* __restrict__ A,
                               const __hip_bfloat16* __restrict__ Bt,
                               const float* __restrict__ bias0,
                               const float* __restrict__ bias1,
                               const float* __restrict__ bias2,
                               short* __restrict__ qbuf,
                               short* __restrict__ kbuf,
                               short* __restrict__ vtbuf,
                               float* __restrict__ outf) {
    constexpr int K = 2048;
    constexpr int KT = 32;  // K / 64
    __shared__ short As[2][2][128 * 64];  // [slot][mhalf] 16KB each
    __shared__ short Bs[2][2][128 * 64];  // [slot][nhalf]

    const int t = threadIdx.x, lane = t & 63, wid = t >> 6;
    const int lr = lane & 15, lg = lane >> 4;
    const int wm = wid >> 2, wn = wid & 3;

    // bijective XCD swizzle (grid counts divisible by 8)
    int nwg = gridDim.x * gridDim.y;
    int orig = blockIdx.y * gridDim.x + blockIdx.x;
    int swz = (orig & 7) * (nwg >> 3) + (orig >> 3);
    int bx = swz % gridDim.x, by = swz / gridDim.x;
    const int n0 = bx * 256, m0 = by * 256;

    const __hip_bfloat16* Ab = A + (size_t)m0 * K;
    const __hip_bfloat16* Bb = Bt + (size_t)n0 * K;

    auto stageA = [&](int s, int kt, int h) {
#pragma unroll
        for (int i = 0; i < 2; ++i) {
            int flat = i * 512 + t;
            int row = flat >> 3, p = flat & 7;
            int col = (p ^ (row & 7)) << 3;
            load_lds16(Ab + (size_t)(h * 128 + row) * K + kt * 64 + col,
                       &As[s][h][(i * 512 + wid * 64) * 8]);
        }
    };
    auto stageB = [&](int s, int kt, int h) {
#pragma unroll
        for (int i = 0; i < 2; ++i) {
            int flat = i * 512 + t;
            int row = flat >> 3, p = flat & 7;
            int col = (p ^ (row & 7)) << 3;
            load_lds16(Bb + (size_t)(h * 128 + row) * K + kt * 64 + col,
                       &Bs[s][h][(i * 512 + wid * 64) * 8]);
        }
    };
    auto ldsA = [&](int s, int qm, short8 (&dst)[4][2]) {
#pragma unroll
        for (int mi = 0; mi < 4; ++mi)
#pragma unroll
            for (int kk = 0; kk < 2; ++kk) {
                int row = wm * 64 + mi * 16 + lr;
                int c = lg + kk * 4;
                dst[mi][kk] = *(const short8*)&As[s][qm][row * 64 + ((c ^ (row & 7)) << 3)];
            }
    };
    auto ldsB = [&](int s, int qn, short8 (&dst)[2][2]) {
#pragma unroll
        for (int ni = 0; ni < 2; ++ni)
#pragma unroll
            for (int kk = 0; kk < 2; ++kk) {
                int row = wn * 32 + ni * 16 + lr;
                int c = lg + kk * 4;
                dst[ni][kk] = *(const short8*)&Bs[s][qn][row * 64 + ((c ^ (row & 7)) << 3)];
            }
    };

    floatx4 acc[8][4];
#pragma unroll
    for (int i = 0; i < 8; ++i)
#pragma unroll
        for (int j = 0; j < 4; ++j) acc[i][j] = (floatx4){0.f, 0.f, 0.f, 0.f};

    short8 af[4][2], b0f[2][2], b1f[2][2];

#define BAR1 __builtin_amdgcn_s_barrier(); \
             asm volatile("s_waitcnt lgkmcnt(0)" ::: "memory")
#define BAR2 __builtin_amdgcn_s_barrier()
#define VM4  asm volatile("s_waitcnt vmcnt(4)" ::: "memory")
#define MF(MOFF, NOFF, BF)                                                     \
    __builtin_amdgcn_s_setprio(1);                                             \
    _Pragma("unroll") for (int mi = 0; mi < 4; ++mi)                           \
    _Pragma("unroll") for (int ni = 0; ni < 2; ++ni)                           \
    _Pragma("unroll") for (int kk = 0; kk < 2; ++kk)                           \
        acc[MOFF + mi][NOFF + ni] = __builtin_amdgcn_mfma_f32_16x16x32_bf16(   \
            af[mi][kk], BF[ni][kk], acc[MOFF + mi][NOFF + ni], 0, 0, 0);       \
    __builtin_amdgcn_s_setprio(0)

    // prologue: K-tile 0 fully + K-tile 1 halves 0 -> vmcnt(4) leaves kt1-h0 flying
    stageA(0, 0, 0); stageB(0, 0, 0); stageA(0, 0, 1); stageB(0, 0, 1);
    stageA(1, 1, 0); stageB(1, 1, 0);
    VM4;
    __builtin_amdgcn_s_barrier();

    for (int it = 0; it < KT / 2; ++it) {
        int k1 = 2 * it + 1;
        int k2 = (2 * it + 2 < KT) ? 2 * it + 2 : KT - 1;  // clamp: garbage stage,
        int k3 = (2 * it + 3 < KT) ? 2 * it + 3 : KT - 1;  // never read (in-bounds)
        // ---- K-tile 2it (slot 0): quadrants (0,0)(0,1)(1,1)(1,0) ----
        ldsA(0, 0, af); ldsB(0, 0, b0f);
        stageA(1, k1, 1);
        BAR1; MF(0, 0, b0f); BAR2;
        ldsB(0, 1, b1f);
        stageB(1, k1, 1);
        BAR1; MF(0, 2, b1f); BAR2;
        ldsA(0, 1, af);
        stageA(0, k2, 0);
        BAR1; MF(4, 2, b1f); BAR2;
        stageB(0, k2, 0);
        BAR1; MF(4, 0, b0f); VM4; BAR2;
        // ---- K-tile 2it+1 (slot 1) ----
        ldsA(1, 0, af); ldsB(1, 0, b0f);
        stageA(0, k2, 1);
        BAR1; MF(0, 0, b0f); BAR2;
        ldsB(1, 1, b1f);
        stageB(0, k2, 1);
        BAR1; MF(0, 2, b1f); BAR2;
        ldsA(1, 1, af);
        stageA(1, k3, 0);
        BAR1; MF(4, 2, b1f); BAR2;
        stageB(1, k3, 0);
        BAR1; MF(4, 0, b0f); VM4; BAR2;
    }
#undef BAR1
#undef BAR2
#undef VM4
#undef MF

    // epilogue. D frag: col = lane&15 (n), row = lg*4 + r (m).
#pragma unroll
    for (int qn = 0; qn < 2; ++qn)
#pragma unroll
        for (int ni = 0; ni < 2; ++ni) {
            int n = n0 + qn * 128 + wn * 32 + ni * 16 + lr;
            if (MODE == 0) {
                int which = n >> 11, d = n & 2047, h = d >> 7, hd = d & 127;
                const float* bias = (which == 0) ? bias0 : (which == 1) ? bias1 : bias2;
                float bval = bias[d];
                short* buf = (which == 0) ? qbuf : (which == 1) ? kbuf : vtbuf;
#pragma unroll
                for (int qm = 0; qm < 2; ++qm)
#pragma unroll
                    for (int mi = 0; mi < 4; ++mi) {
                        int m = m0 + qm * 128 + wm * 64 + mi * 16 + lg * 4;
                        int b = m >> 11, s = m & 2047;
                        int bh = b * 16 + h;
#pragma unroll
                        for (int r = 0; r < 4; ++r) {
                            float v = acc[qm * 4 + mi][qn * 2 + ni][r] + bval;
                            if (which == 0) v *= 0.08838834764831845f;  // QK scale
                            if (which < 2)
                                buf[((size_t)bh * 2048 + s + r) * 128 + hd] = f2bf(v);
                            else  // V transposed: [BH][HD][S]
                                buf[((size_t)bh * 128 + hd) * 2048 + s + r] = f2bf(v);
                        }
                    }
            } else {
                float bval = bias0[n];
#pragma unroll
                for (int qm = 0; qm < 2; ++qm)
#pragma unroll
                    for (int mi = 0; mi < 4; ++mi) {
                        int m = m0 + qm * 128 + wm * 64 + mi * 16 + lg * 4;
#pragma unroll
                        for (int r = 0; r < 4; ++r)
                            outf[(size_t)(m + r) * 2048 + n] =
                                acc[qm * 4 + mi][qn * 2 + ni][r] + bval;
                    }
            }
        }
}

// ---------------- flash attention (swapped-QK^T, 2-phase dbuf) ----------------
__launch_bounds__(256, 2)
__global__ void attn_kernel(const __hip_bfloat16* __restrict__ qb,
                            const __hip_bfloat16* __restrict__ kb,
                            const __hip_bfloat16* __restrict__ vtb,
                            short* __restrict__ ob) {
    __shared__ short Ks[2][64 * 128];
    __shared__ short Vts[2][128 * 64];
    __shared__ short Pt[4][32 * 64];

    const int t = threadIdx.x, lane = t & 63, w = t >> 6;
    const int lr = lane & 15, lg = lane >> 4;

    int id = blockIdx.y * 16 + blockIdx.x;
    int xcd = id & 7, slot = id >> 3;
    int bh = xcd * 8 + (slot >> 4);
    int qblk = slot & 15;
    const int b = bh >> 4, h = bh & 15;
    const int q0 = qblk * 128;

    const __hip_bfloat16* qB = qb + (size_t)bh * 2048 * 128;
    const __hip_bfloat16* kB = kb + (size_t)bh * 2048 * 128;
    const __hip_bfloat16* vB = vtb + (size_t)bh * 128 * 2048;

    short8 aq[2][4];
#pragma unroll
    for (int mi = 0; mi < 2; ++mi) {
        int row = q0 + w * 32 + mi * 16 + lr;
#pragma unroll
        for (int kk = 0; kk < 4; ++kk)
            aq[mi][kk] = *(const short8*)(qB + (size_t)row * 128 + lg * 8 + kk * 32);
    }

    floatx4 o[2][8];
    float mv[2], lv[2];
#pragma unroll
    for (int mi = 0; mi < 2; ++mi) {
#pragma unroll
        for (int n = 0; n < 8; ++n) o[mi][n] = (floatx4){0.f, 0.f, 0.f, 0.f};
        mv[mi] = -1e30f; lv[mi] = 0.f;
    }

    auto STAGE = [&](int d, int kv) {
#pragma unroll
        for (int i = 0; i < 4; ++i) {
            int fc = i * 256 + t, row = fc >> 4, p = fc & 15;
            load_lds16(kB + (size_t)(kv * 64 + row) * 128 + ((p ^ (row & 15)) << 3),
                       &Ks[d][(i * 256 + w * 64) * 8]);
        }
#pragma unroll
        for (int i = 0; i < 4; ++i) {
            int fc = i * 256 + t, row = fc >> 3, p = fc & 7;
            load_lds16(vB + (size_t)row * 2048 + kv * 64 + ((p ^ (row & 7)) << 3),
                       &Vts[d][(i * 256 + w * 64) * 8]);
        }
    };

    STAGE(0, 0);
    asm volatile("s_waitcnt vmcnt(0)" ::: "memory");
    __builtin_amdgcn_s_barrier();

    int cur = 0;
    for (int kv = 0; kv < 32; ++kv) {
        if (kv < 31) STAGE(cur ^ 1, kv + 1);

        floatx4 sfr[2][4];
#pragma unroll
        for (int mi = 0; mi < 2; ++mi)
#pragma unroll
            for (int tt = 0; tt < 4; ++tt) sfr[mi][tt] = (floatx4){0.f, 0.f, 0.f, 0.f};
        __builtin_amdgcn_s_setprio(1);
#pragma unroll
        for (int tt = 0; tt < 4; ++tt)
#pragma unroll
            for (int kk = 0; kk < 4; ++kk) {
                int row = tt * 16 + lr;
                int c = lg + kk * 4;
                short8 bk = *(const short8*)&Ks[cur][row * 128 + ((c ^ (row & 15)) << 3)];
                sfr[0][tt] = __builtin_amdgcn_mfma_f32_16x16x32_bf16(bk, aq[0][kk], sfr[0][tt], 0, 0, 0);
                sfr[1][tt] = __builtin_amdgcn_mfma_f32_16x16x32_bf16(bk, aq[1][kk], sfr[1][tt], 0, 0, 0);
            }
        __builtin_amdgcn_s_setprio(0);

#pragma unroll
        for (int mi = 0; mi < 2; ++mi) {
            float pm = sfr[mi][0][0];
#pragma unroll
            for (int tt = 0; tt < 4; ++tt)
#pragma unroll
                for (int r = 0; r < 4; ++r) pm = fmaxf(pm, sfr[mi][tt][r]);
            pm = fmaxf(pm, __shfl_xor(pm, 16));
            pm = fmaxf(pm, __shfl_xor(pm, 32));
            if (!__all(pm - mv[mi] <= 8.f)) {
                float mn = fmaxf(mv[mi], pm);
                float alpha = __expf(mv[mi] - mn);
                mv[mi] = mn;
                lv[mi] *= alpha;
#pragma unroll
                for (int n = 0; n < 8; ++n) o[mi][n] *= alpha;
            }
            float m = mv[mi], ls = 0.f;
            u32 pk[8];
#pragma unroll
            for (int tt = 0; tt < 4; ++tt) {
                float p0 = __expf(sfr[mi][tt][0] - m);
                float p1 = __expf(sfr[mi][tt][1] - m);
                float p2 = __expf(sfr[mi][tt][2] - m);
                float p3 = __expf(sfr[mi][tt][3] - m);
                ls += (p0 + p1) + (p2 + p3);
                pk[tt * 2] = cvt_pk_bf16(p0, p1);
                pk[tt * 2 + 1] = cvt_pk_bf16(p2, p3);
            }
            ls += __shfl_xor(ls, 16);
            ls += __shfl_xor(ls, 32);
            lv[mi] += ls;
#pragma unroll
            for (int tt = 0; tt < 4; ++tt) {
                int hgran = tt * 2 + (lg >> 1);
                int idx = (mi * 16 + lr) * 64 + ((hgran ^ (lr & 7)) * 8) + (lg & 1) * 4;
                *(uint2*)&Pt[w][idx] = make_uint2(pk[tt * 2], pk[tt * 2 + 1]);
            }
        }

        short8 pa[2][2];
#pragma unroll
        for (int mi = 0; mi < 2; ++mi)
#pragma unroll
            for (int kk = 0; kk < 2; ++kk) {
                int hgran = kk * 4 + lg;
                int idx = (mi * 16 + lr) * 64 + ((hgran ^ (lr & 7)) * 8);
                pa[mi][kk] = *(const short8*)&Pt[w][idx];
            }
        __builtin_amdgcn_s_setprio(1);
#pragma unroll
        for (int n = 0; n < 8; ++n)
#pragma unroll
            for (int kk = 0; kk < 2; ++kk) {
                int vrow = n * 16 + lr;
                int c = lg + kk * 4;
                short8 bv = *(const short8*)&Vts[cur][vrow * 64 + ((c ^ (vrow & 7)) << 3)];
                o[0][n] = __builtin_amdgcn_mfma_f32_16x16x32_bf16(bv, pa[0][kk], o[0][n], 0, 0, 0);
                o[1][n] = __builtin_amdgcn_mfma_f32_16x16x32_bf16(bv, pa[1][kk], o[1][n], 0, 0, 0);
            }
        __builtin_amdgcn_s_setprio(0);

        asm volatile("s_waitcnt vmcnt(0)" ::: "memory");
        __builtin_amdgcn_s_barrier();
        cur ^= 1;
    }

#pragma unroll
    for (int mi = 0; mi < 2; ++mi) {
        float inv = 1.f / lv[mi];
        int s = q0 + w * 32 + mi * 16 + lr;
        size_t base = ((size_t)b * 2048 + s) * 2048 + h * 128;
#pragma unroll
        for (int n = 0; n < 8; ++n) {
            short4v vv;
#pragma unroll
            for (int r = 0; r < 4; ++r) vv[r] = f2bf(o[mi][n][r] * inv);
            *(short4v*)&ob[base + n * 16 + lg * 4] = vv;
        }
    }
}

extern "C" void kernel_launch(void* const* d_in, const int* in_sizes, int n_in,
                              void* d_out, int out_size, void* d_ws, size_t ws_size,
                              hipStream_t stream) {
    (void)in_sizes; (void)n_in; (void)out_size; (void)ws_size;
    const float* x  = (const float*)d_in[0];
    const float* wq = (const float*)d_in[1];
    const float* bq = (const float*)d_in[2];
    const float* wk = (const float*)d_in[3];
    const float* bk = (const float*)d_in[4];
    const float* wv = (const float*)d_in[5];
    const float* bv = (const float*)d_in[6];
    const float* wo = (const float*)d_in[7];
    const float* bo = (const float*)d_in[8];
    float* out = (float*)d_out;

    char* ws = (char*)d_ws;
    const size_t SZ = (size_t)33554432;  // 8192*2048*2 bytes
    __hip_bfloat16* xbf = (__hip_bfloat16*)(ws);
    short* wt    = (short*)(ws + SZ);
    short* qbuf  = (short*)(ws + 2 * SZ);
    short* kbuf  = (short*)(ws + 3 * SZ);
    short* vtbuf = (short*)(ws + 4 * SZ);
    short* obuf  = (short*)(ws);  // aliases xbf (dead after gemm<0>)

    cast_x_kernel<<<8192, 256, 0, stream>>>(x, xbf, 2097152);
    transpose_cast_kernel<<<dim3(64, 64, 4), dim3(32, 8), 0, stream>>>(wq, wk, wv, wo, wt);
    gemm256_kernel<0><<<dim3(24, 32), 512, 0, stream>>>(
        xbf, (const __hip_bfloat16*)wt, bq, bk, bv, qbuf, kbuf, vtbuf, nullptr);
    attn_kernel<<<dim3(16, 64), 256, 0, stream>>>(
        (const __hip_bfloat16*)qbuf, (const __hip_bfloat16*)kbuf,
        (const __hip_bfloat16*)vtbuf, obuf);
    gemm256_kernel<1><<<dim3(8, 32), 512, 0, stream>>>(
        (const __hip_bfloat16*)obuf, (const __hip_bfloat16*)(wt + (size_t)6144 * 2048),
        bo, nullptr, nullptr, nullptr, nullptr, nullptr, out);
}